// Round 16
// baseline (270.088 us; speedup 1.0000x reference)
//
#include <hip/hip_runtime.h>
#include <stdint.h>

// LinearBin: out = x @ sign(W)^T + bias   (B=131072, IN=OUT=512, fp32)
// v16: v8 (best, 137.8us) x 4 strips per block = write-tail amortization.
//      Each block: 4 consecutive 64-row strips, same LDS. Per strip:
//      K-loop -> epilogue stores (fire-and-forget) -> RAW s_barrier (no
//      vmcnt drain!) -> stage next strip -> lgkmcnt(0)+barrier -> repeat.
//      Strip-s stores drain under strip-s+1 stage+K-loop; only the last
//      strip's stores are exposed. grid=512 = one generation (2 blocks/CU).

#define BATCH   131072
#define IN_F    512
#define OUT_F   512
#define BM      64
#define NS      4             // strips per block
#define NKT     32            // K-steps of 16

using f32x4  = __attribute__((ext_vector_type(4))) float;
using f32x16 = __attribute__((ext_vector_type(16))) float;
using short8 = __attribute__((ext_vector_type(8))) short;
using usv8   = __attribute__((ext_vector_type(8))) unsigned short;
using u32    = uint32_t;

// ---------------- prep: binarize W into 32x32x16-fragment-major bf16 --------
// (verified r6/r8)  wf[((kt*16+nf)*64+l)*8+j] = sign(W[nf*32+(l&31)][kt*16+(l>>5)*8+j])
__global__ void prep_w(const float* __restrict__ W, unsigned short* __restrict__ wf) {
    int t = blockIdx.x * blockDim.x + threadIdx.x; // 32768 threads
    int l  = t & 63;
    int nf = (t >> 6) & 15;
    int kt = t >> 10;
    int n = nf * 32 + (l & 31);
    int k = kt * 16 + ((l >> 5) << 3);
    const float* src = W + (size_t)n * IN_F + k;
    f32x4 w0 = *(const f32x4*)(src);
    f32x4 w1 = *(const f32x4*)(src + 4);
    usv8 o;
#pragma unroll
    for (int j = 0; j < 4; ++j) {
        o[j]     = (w0[j] >= 0.0f) ? 0x3F80u : 0xBF80u; // +1.0 / -1.0 bf16
        o[j + 4] = (w1[j] >= 0.0f) ? 0x3F80u : 0xBF80u;
    }
    *(usv8*)(wf + (size_t)t * 8) = o;
}

// ---------------- GEMM ----------------
__global__ __launch_bounds__(512, 2) void gemm_bin(
    const float* __restrict__ X, const unsigned short* __restrict__ WF,
    const float* __restrict__ bias, float* __restrict__ out) {

    // 64 rows x 512 bf16, row stride 1KB, 16B slots XOR-swizzled by (row&7).
    __shared__ __align__(16) unsigned short lds[BM * IN_F]; // 64KB

    const int tid  = threadIdx.x;
    const int lane = tid & 63;
    const int wv   = tid >> 6;              // 0..7 -> 64-col strip
    const int m0   = blockIdx.x * (NS * BM);   // grid = 512

    // ---- staging geometry (v8-verbatim) ----
    const int sr  = tid >> 3;               // 0..63
    const int sg  = tid & 7;
    char* lrow    = (char*)lds + sr * 1024;
    const int swz = (sr & 7) << 4;

#define STAGE(s_)                                                              \
    {                                                                          \
        const float* xr = X + (size_t)(m0 + (s_) * BM + sr) * IN_F;            \
        _Pragma("unroll")                                                      \
        for (int p = 0; p < 8; ++p) {                                          \
            const int f0 = sg * 8 + p * 64;                                    \
            f32x4 a = *(const f32x4*)(xr + f0);                                \
            f32x4 b = *(const f32x4*)(xr + f0 + 4);                            \
            u32 w0, w1, w2, w3;                                                \
            asm("v_cvt_pk_bf16_f32 %0, %1, %2" : "=v"(w0)                      \
                : "v"(a[0]), "v"(a[1]));                                       \
            asm("v_cvt_pk_bf16_f32 %0, %1, %2" : "=v"(w1)                      \
                : "v"(a[2]), "v"(a[3]));                                       \
            asm("v_cvt_pk_bf16_f32 %0, %1, %2" : "=v"(w2)                      \
                : "v"(b[0]), "v"(b[1]));                                       \
            asm("v_cvt_pk_bf16_f32 %0, %1, %2" : "=v"(w3)                      \
                : "v"(b[2]), "v"(b[3]));                                       \
            union { u32 w[4]; usv8 v; } pk;                                    \
            pk.w[0] = w0; pk.w[1] = w1; pk.w[2] = w2; pk.w[3] = w3;            \
            *(usv8*)(lrow + ((sg * 16 + p * 128) ^ swz)) = pk.v;               \
        }                                                                      \
    }

    // ---- A/B fragment geometry (v8-verbatim) ----
    const int arow  = (lane & 31) * 1024;
    const int ak4   = (lane >> 5) << 4;
    const int aswz  = (lane & 7) << 4;
    const char* lptr = (const char*)lds;
    const short8* wb = (const short8*)(WF) + ((size_t)(wv * 2) * 64 + lane);

#define LDA(dst, kt_)                                                          \
    {                                                                          \
        const int koff_ = ((kt_) * 32 + ak4) ^ aswz;                           \
        dst[0] = *(const short8*)(lptr + arow + koff_);                        \
        dst[1] = *(const short8*)(lptr + arow + 32768 + koff_);                \
    }
#define LDB(dst, kt_)                                                          \
    {                                                                          \
        _Pragma("unroll")                                                      \
        for (int fn = 0; fn < 2; ++fn)                                         \
            dst[fn] = wb[(kt_) * 1024 + fn * 64];                              \
    }

    const float bv0 = bias[wv * 64 + (lane & 31)];
    const float bv1 = bias[wv * 64 + 32 + (lane & 31)];
    const int c     = lane & 31;
    const int rbase = (lane >> 5) << 2;

    // ---- prologue: stage strip 0 ----
    STAGE(0);
    __syncthreads();

    f32x16 acc[2][2];
#pragma unroll 1
    for (int s = 0; s < NS; ++s) {
        // acc init with bias
#pragma unroll
        for (int r = 0; r < 16; ++r) {
            acc[0][0][r] = bv0; acc[0][1][r] = bv1;
            acc[1][0][r] = bv0; acc[1][1][r] = bv1;
        }

        // K-loop (v8-verbatim: A +1-deep, B +2-deep rotation)
        short8 af[2][2], bf[2][2];
        LDA(af[0], 0);
        LDB(bf[0], 0);
        LDB(bf[1], 1);
#pragma unroll
        for (int kt = 0; kt < NKT; ++kt) {
            const int cur = kt & 1;
            if (kt < NKT - 1) LDA(af[cur ^ 1], kt + 1);
#pragma unroll
            for (int rg = 0; rg < 2; ++rg)
#pragma unroll
                for (int fn = 0; fn < 2; ++fn)
                    acc[rg][fn] = __builtin_amdgcn_mfma_f32_32x32x16_bf16(
                        af[cur][rg], bf[cur][fn], acc[rg][fn], 0, 0, 0);
            if (kt < NKT - 2) LDB(bf[cur], kt + 2);
        }

        // epilogue stores for strip s: fire-and-forget (no waitcnt here)
        {
            const size_t ms = (size_t)(m0 + s * BM);
#pragma unroll
            for (int rg = 0; rg < 2; ++rg)
#pragma unroll
                for (int fn = 0; fn < 2; ++fn)
#pragma unroll
                    for (int r = 0; r < 16; ++r) {
                        const int row = rg * 32 + (r & 3) + 8 * (r >> 2) + rbase;
                        out[(ms + row) * OUT_F + wv * 64 + fn * 32 + c] =
                            acc[rg][fn][r];
                    }
        }

        if (s + 1 < NS) {
            // RAW barrier: all waves finished their LDS reads (data already
            // consumed by MFMAs). Crucially: NO vmcnt(0) drain -> the stores
            // above keep draining under the next stage + K-loop.
            __builtin_amdgcn_sched_barrier(0);
            __builtin_amdgcn_s_barrier();
            __builtin_amdgcn_sched_barrier(0);
            STAGE(s + 1);
            asm volatile("s_waitcnt lgkmcnt(0)" ::: "memory");
            __builtin_amdgcn_sched_barrier(0);
            __builtin_amdgcn_s_barrier();
            __builtin_amdgcn_sched_barrier(0);
        }
    }
#undef STAGE
#undef LDA
#undef LDB
}

extern "C" void kernel_launch(void* const* d_in, const int* in_sizes, int n_in,
                              void* d_out, int out_size, void* d_ws, size_t ws_size,
                              hipStream_t stream) {
    const float* X    = (const float*)d_in[0];
    const float* W    = (const float*)d_in[1];
    const float* bias = (const float*)d_in[2];
    float* o          = (float*)d_out;
    unsigned short* wf = (unsigned short*)d_ws; // 512KB fragment-major binarized W

    hipLaunchKernelGGL(prep_w, dim3(128), dim3(256), 0, stream, W, wf);
    hipLaunchKernelGGL(gemm_bin, dim3(BATCH / (BM * NS)), dim3(512), 0, stream,
                       X, wf, bias, o);
}

// Round 17
// 159.628 us; speedup vs baseline: 1.6920x; 1.6920x over previous
//
#include <hip/hip_runtime.h>
#include <stdint.h>

// LinearBin: out = x @ sign(W)^T + bias   (B=131072, IN=OUT=512, fp32)
// v17: v16 (write-tail amortization) spill-proofed. Strip loop FULLY
//      unrolled -> straight-line = 4 copies of the proven v8 body, each
//      with independent SSA acc (AGPR-allocatable). Fire-and-forget stores
//      + raw s_barrier (no vmcnt drain) between strips; only the final
//      strip's write burst is exposed. grid=512, 2 blocks/CU, one generation.

#define BATCH   131072
#define IN_F    512
#define OUT_F   512
#define BM      64
#define NS      4             // strips per block
#define NKT     32            // K-steps of 16

using f32x4  = __attribute__((ext_vector_type(4))) float;
using f32x16 = __attribute__((ext_vector_type(16))) float;
using short8 = __attribute__((ext_vector_type(8))) short;
using usv8   = __attribute__((ext_vector_type(8))) unsigned short;
using u32    = uint32_t;

// ---------------- prep: binarize W into 32x32x16-fragment-major bf16 --------
// (verified r6/r8)  wf[((kt*16+nf)*64+l)*8+j] = sign(W[nf*32+(l&31)][kt*16+(l>>5)*8+j])
__global__ void prep_w(const float* __restrict__ W, unsigned short* __restrict__ wf) {
    int t = blockIdx.x * blockDim.x + threadIdx.x; // 32768 threads
    int l  = t & 63;
    int nf = (t >> 6) & 15;
    int kt = t >> 10;
    int n = nf * 32 + (l & 31);
    int k = kt * 16 + ((l >> 5) << 3);
    const float* src = W + (size_t)n * IN_F + k;
    f32x4 w0 = *(const f32x4*)(src);
    f32x4 w1 = *(const f32x4*)(src + 4);
    usv8 o;
#pragma unroll
    for (int j = 0; j < 4; ++j) {
        o[j]     = (w0[j] >= 0.0f) ? 0x3F80u : 0xBF80u; // +1.0 / -1.0 bf16
        o[j + 4] = (w1[j] >= 0.0f) ? 0x3F80u : 0xBF80u;
    }
    *(usv8*)(wf + (size_t)t * 8) = o;
}

// ---------------- GEMM ----------------
__global__ __launch_bounds__(512, 2) void gemm_bin(
    const float* __restrict__ X, const unsigned short* __restrict__ WF,
    const float* __restrict__ bias, float* __restrict__ out) {

    // 64 rows x 512 bf16, row stride 1KB, 16B slots XOR-swizzled by (row&7).
    __shared__ __align__(16) unsigned short lds[BM * IN_F]; // 64KB

    const int tid  = threadIdx.x;
    const int lane = tid & 63;
    const int wv   = tid >> 6;              // 0..7 -> 64-col strip
    const int m0   = blockIdx.x * (NS * BM);   // grid = 512

    // ---- staging geometry (v8-verbatim) ----
    const int sr  = tid >> 3;               // 0..63
    const int sg  = tid & 7;
    char* lrow    = (char*)lds + sr * 1024;
    const int swz = (sr & 7) << 4;

#define STAGE(s_)                                                              \
    {                                                                          \
        const float* xr = X + (size_t)(m0 + (s_) * BM + sr) * IN_F;            \
        _Pragma("unroll")                                                      \
        for (int p = 0; p < 8; ++p) {                                          \
            const int f0 = sg * 8 + p * 64;                                    \
            f32x4 a = *(const f32x4*)(xr + f0);                                \
            f32x4 b = *(const f32x4*)(xr + f0 + 4);                            \
            u32 w0, w1, w2, w3;                                                \
            asm("v_cvt_pk_bf16_f32 %0, %1, %2" : "=v"(w0)                      \
                : "v"(a[0]), "v"(a[1]));                                       \
            asm("v_cvt_pk_bf16_f32 %0, %1, %2" : "=v"(w1)                      \
                : "v"(a[2]), "v"(a[3]));                                       \
            asm("v_cvt_pk_bf16_f32 %0, %1, %2" : "=v"(w2)                      \
                : "v"(b[0]), "v"(b[1]));                                       \
            asm("v_cvt_pk_bf16_f32 %0, %1, %2" : "=v"(w3)                      \
                : "v"(b[2]), "v"(b[3]));                                       \
            union { u32 w[4]; usv8 v; } pk;                                    \
            pk.w[0] = w0; pk.w[1] = w1; pk.w[2] = w2; pk.w[3] = w3;            \
            *(usv8*)(lrow + ((sg * 16 + p * 128) ^ swz)) = pk.v;               \
        }                                                                      \
    }

    // ---- A/B fragment geometry (v8-verbatim) ----
    const int arow  = (lane & 31) * 1024;
    const int ak4   = (lane >> 5) << 4;
    const int aswz  = (lane & 7) << 4;
    const char* lptr = (const char*)lds;
    const short8* wb = (const short8*)(WF) + ((size_t)(wv * 2) * 64 + lane);

#define LDA(dst, kt_)                                                          \
    {                                                                          \
        const int koff_ = ((kt_) * 32 + ak4) ^ aswz;                           \
        dst[0] = *(const short8*)(lptr + arow + koff_);                        \
        dst[1] = *(const short8*)(lptr + arow + 32768 + koff_);                \
    }
#define LDB(dst, kt_)                                                          \
    {                                                                          \
        _Pragma("unroll")                                                      \
        for (int fn = 0; fn < 2; ++fn)                                         \
            dst[fn] = wb[(kt_) * 1024 + fn * 64];                              \
    }

    const float bv0 = bias[wv * 64 + (lane & 31)];
    const float bv1 = bias[wv * 64 + 32 + (lane & 31)];
    const int c     = lane & 31;
    const int rbase = (lane >> 5) << 2;

    // ---- prologue: stage strip 0 ----
    STAGE(0);
    __syncthreads();

#pragma unroll            // FULL unroll: straight-line, per-strip SSA acc
    for (int s = 0; s < NS; ++s) {
        f32x16 acc[2][2];
#pragma unroll
        for (int r = 0; r < 16; ++r) {
            acc[0][0][r] = bv0; acc[0][1][r] = bv1;
            acc[1][0][r] = bv0; acc[1][1][r] = bv1;
        }

        // K-loop (v8-verbatim: A +1-deep, B +2-deep rotation)
        short8 af[2][2], bf[2][2];
        LDA(af[0], 0);
        LDB(bf[0], 0);
        LDB(bf[1], 1);
#pragma unroll
        for (int kt = 0; kt < NKT; ++kt) {
            const int cur = kt & 1;
            if (kt < NKT - 1) LDA(af[cur ^ 1], kt + 1);
#pragma unroll
            for (int rg = 0; rg < 2; ++rg)
#pragma unroll
                for (int fn = 0; fn < 2; ++fn)
                    acc[rg][fn] = __builtin_amdgcn_mfma_f32_32x32x16_bf16(
                        af[cur][rg], bf[cur][fn], acc[rg][fn], 0, 0, 0);
            if (kt < NKT - 2) LDB(bf[cur], kt + 2);
        }

        // epilogue stores for strip s: fire-and-forget (no waitcnt here)
        {
            const size_t ms = (size_t)(m0 + s * BM);
#pragma unroll
            for (int rg = 0; rg < 2; ++rg)
#pragma unroll
                for (int fn = 0; fn < 2; ++fn)
#pragma unroll
                    for (int r = 0; r < 16; ++r) {
                        const int row = rg * 32 + (r & 3) + 8 * (r >> 2) + rbase;
                        out[(ms + row) * OUT_F + wv * 64 + fn * 32 + c] =
                            acc[rg][fn][r];
                    }
        }

        if (s + 1 < NS) {
            // RAW barrier: LDS data already consumed; NO vmcnt(0) drain, so
            // strip-s stores keep draining under strip-(s+1) stage + K-loop.
            __builtin_amdgcn_sched_barrier(0);
            __builtin_amdgcn_s_barrier();
            __builtin_amdgcn_sched_barrier(0);
            STAGE(s + 1);
            asm volatile("s_waitcnt lgkmcnt(0)" ::: "memory");
            __builtin_amdgcn_sched_barrier(0);
            __builtin_amdgcn_s_barrier();
            __builtin_amdgcn_sched_barrier(0);
        }
    }
#undef STAGE
#undef LDA
#undef LDB
}

extern "C" void kernel_launch(void* const* d_in, const int* in_sizes, int n_in,
                              void* d_out, int out_size, void* d_ws, size_t ws_size,
                              hipStream_t stream) {
    const float* X    = (const float*)d_in[0];
    const float* W    = (const float*)d_in[1];
    const float* bias = (const float*)d_in[2];
    float* o          = (float*)d_out;
    unsigned short* wf = (unsigned short*)d_ws; // 512KB fragment-major binarized W

    hipLaunchKernelGGL(prep_w, dim3(128), dim3(256), 0, stream, W, wf);
    hipLaunchKernelGGL(gemm_bin, dim3(BATCH / (BM * NS)), dim3(512), 0, stream,
                       X, wf, bias, o);
}